// Round 1
// baseline (190.563 us; speedup 1.0000x reference)
//
#include <hip/hip_runtime.h>

#define DD 5
#define SS 32
#define F_N 100000
#define V_N 60000
#define E_N (F_N * DD)

__device__ __forceinline__ float lse2(float a, float b) {
    float m = fmaxf(a, b);
    return m + __logf(__expf(a - m) + __expf(b - m));
}

// ---------------- Kernel 1: factor->var messages + var_beliefs scatter ----------------
// One thread per factor. Edges of factor f are e = f*5 + d, with var-dim d.
__global__ __launch_bounds__(256) void k_f2v(
    const float* __restrict__ prv_v2f,   // [E,2]
    const float* __restrict__ prv_f2v,   // [E,2]
    const float* __restrict__ prv_fb,    // [F,32]
    const int*   __restrict__ edge_v,    // [E]
    float* __restrict__ out_f2v,         // [E,2]
    float* __restrict__ out_vb)          // [V,2] (pre-zeroed)
{
    int f = blockIdx.x * blockDim.x + threadIdx.x;
    if (f >= F_N) return;

    float fb[SS];
    const float4* rp = (const float4*)(prv_fb + (size_t)f * SS);
    #pragma unroll
    for (int i = 0; i < 8; ++i) {
        float4 v = rp[i];
        fb[i*4+0] = v.x; fb[i*4+1] = v.y; fb[i*4+2] = v.z; fb[i*4+3] = v.w;
    }
    float M = fb[0];
    #pragma unroll
    for (int s = 1; s < SS; ++s) M = fmaxf(M, fb[s]);
    float Es[SS];
    #pragma unroll
    for (int s = 0; s < SS; ++s) Es[s] = __expf(fb[s] - M);

    #pragma unroll
    for (int d = 0; d < DD; ++d) {
        const int shift = 4 - d;
        float s0 = 0.f, s1 = 0.f;
        #pragma unroll
        for (int s = 0; s < SS; ++s) {
            if ((s >> shift) & 1) s1 += Es[s]; else s0 += Es[s];
        }
        float L0 = M + __logf(s0);
        float L1 = M + __logf(s1);
        int e = f * DD + d;
        float2 m = *(const float2*)(prv_v2f + 2*(size_t)e);
        float2 p = *(const float2*)(prv_f2v + 2*(size_t)e);
        float a0 = 0.5f * (L0 - m.x) + 0.5f * p.x;
        float a1 = 0.5f * (L1 - m.y) + 0.5f * p.y;
        float z = lse2(a0, a1);
        a0 -= z; a1 -= z;
        *(float2*)(out_f2v + 2*(size_t)e) = make_float2(a0, a1);
        int v = edge_v[e];
        atomicAdd(out_vb + 2*(size_t)v,     a0);
        atomicAdd(out_vb + 2*(size_t)v + 1, a1);
    }
}

// ---------------- Kernel 2: var->factor messages + factor beliefs (fused MLPs) ----------------
__global__ __launch_bounds__(256) void k_v2f_fb(
    const float* __restrict__ pot,       // [F,32]
    const float* __restrict__ W1, const float* __restrict__ b1,
    const float* __restrict__ W2, const float* __restrict__ b2,
    const float* __restrict__ W3, const float* __restrict__ b3,
    const float* __restrict__ W4, const float* __restrict__ b4,
    const int*   __restrict__ edge_v,    // [E]
    const float* __restrict__ f2v,       // [E,2]  (output of K1)
    const float* __restrict__ vb,        // [V,2]  (output of K1)
    float* __restrict__ out_v2f,         // [E,2]
    float* __restrict__ out_fb)          // [F,32]
{
    // Fold each 2-layer MLP + residual into one affine map, staged in LDS.
    __shared__ float sW1[SS*SS], sW2[SS*SS], sb1[SS], sb2[SS];
    const int t = threadIdx.x;
    for (int idx = t; idx < SS*SS; idx += 256) {
        const int i = idx >> 5, k = idx & 31;
        float acc1 = 0.f, acc2 = 0.f;
        #pragma unroll
        for (int j = 0; j < SS; ++j) {
            acc1 += W2[i*SS+j] * W1[j*SS+k];
            acc2 += W4[i*SS+j] * W3[j*SS+k];
        }
        sW1[idx] = 0.5f*acc1 + (i == k ? 0.5f : 0.f);
        sW2[idx] = 0.5f*acc2 + (i == k ? 0.5f : 0.f);
    }
    if (t < SS) {
        float a1 = 0.f, a2 = 0.f;
        #pragma unroll
        for (int j = 0; j < SS; ++j) {
            a1 += W2[t*SS+j] * b1[j];
            a2 += W4[t*SS+j] * b3[j];
        }
        sb1[t] = 0.5f * (a1 + b2[t]);
        sb2[t] = 0.5f * (a2 + b4[t]);
    }
    __syncthreads();

    int f = blockIdx.x * blockDim.x + t;
    if (f >= F_N) return;

    float x[SS];
    #pragma unroll
    for (int s = 0; s < SS; ++s) x[s] = 0.f;

    #pragma unroll
    for (int d = 0; d < DD; ++d) {
        const int shift = 4 - d;
        int e = f * DD + d;
        float2 m = *(const float2*)(f2v + 2*(size_t)e);
        int v = edge_v[e];
        float2 B = *(const float2*)(vb + 2*(size_t)v);
        float a0 = B.x - m.x, a1 = B.y - m.y;
        float z = lse2(a0, a1);
        a0 -= z; a1 -= z;
        *(float2*)(out_v2f + 2*(size_t)e) = make_float2(a0, a1);
        #pragma unroll
        for (int s = 0; s < SS; ++s) x[s] += ((s >> shift) & 1) ? a1 : a0;
    }

    // y = pot[f] + 5*beff1 + x @ Weff1^T
    float y[SS];
    #pragma unroll
    for (int i = 0; i < SS; ++i) {
        float acc = 5.0f * sb1[i];
        #pragma unroll
        for (int k = 0; k < SS; ++k) acc += x[k] * sW1[i*SS+k];
        y[i] = acc;
    }
    const float4* pp = (const float4*)(pot + (size_t)f * SS);
    #pragma unroll
    for (int i = 0; i < 8; ++i) {
        float4 v = pp[i];
        y[i*4+0] += v.x; y[i*4+1] += v.y; y[i*4+2] += v.z; y[i*4+3] += v.w;
    }
    // out = beff2 + y @ Weff2^T
    float4* op = (float4*)(out_fb + (size_t)f * SS);
    #pragma unroll
    for (int i = 0; i < 8; ++i) {
        float o[4];
        #pragma unroll
        for (int j = 0; j < 4; ++j) {
            float acc = sb2[i*4+j];
            #pragma unroll
            for (int k = 0; k < SS; ++k) acc += y[k] * sW2[(i*4+j)*SS+k];
            o[j] = acc;
        }
        op[i] = make_float4(o[0], o[1], o[2], o[3]);
    }
}

extern "C" void kernel_launch(void* const* d_in, const int* in_sizes, int n_in,
                              void* d_out, int out_size, void* d_ws, size_t ws_size,
                              hipStream_t stream) {
    const float* prv_v2f = (const float*)d_in[0];
    const float* prv_f2v = (const float*)d_in[1];
    const float* prv_fb  = (const float*)d_in[2];
    const float* pot     = (const float*)d_in[3];
    const float* W1 = (const float*)d_in[4];
    const float* b1 = (const float*)d_in[5];
    const float* W2 = (const float*)d_in[6];
    const float* b2 = (const float*)d_in[7];
    const float* W3 = (const float*)d_in[8];
    const float* b3 = (const float*)d_in[9];
    const float* W4 = (const float*)d_in[10];
    const float* b4 = (const float*)d_in[11];
    const int* edge_v = (const int*)d_in[13];

    float* out   = (float*)d_out;
    float* o_v2f = out;                         // [E,2]  = 1,000,000
    float* o_f2v = out + 2*(size_t)E_N;         // [E,2]  = 1,000,000
    float* o_fb  = out + 4*(size_t)E_N;         // [F,32] = 3,200,000
    float* o_vb  = o_fb + (size_t)F_N * SS;     // [V,2]  =   120,000

    hipMemsetAsync(o_vb, 0, (size_t)V_N * 2 * sizeof(float), stream);

    const int blocks = (F_N + 255) / 256;
    k_f2v<<<blocks, 256, 0, stream>>>(prv_v2f, prv_f2v, prv_fb, edge_v, o_f2v, o_vb);
    k_v2f_fb<<<blocks, 256, 0, stream>>>(pot, W1, b1, W2, b2, W3, b3, W4, b4,
                                         edge_v, o_f2v, o_vb, o_v2f, o_fb);
}